// Round 6
// baseline (197.758 us; speedup 1.0000x reference)
//
#include <hip/hip_runtime.h>
#include <hip/hip_bf16.h>
#include <math.h>

#define N_ATOMS 10000
#define N_PAIRS 160000
#define FDIM 256
#define GDIM 16
#define HDIM 64
#define HIDDIM 256
#define MLP_IN 640
#define MLP_OUT 258

typedef __attribute__((ext_vector_type(8))) short short8;
typedef __attribute__((ext_vector_type(4))) float f32x4;

__device__ __forceinline__ float gelu_exact(float x) {
    return 0.5f * x * (1.0f + erff(x * 0.70710678118654752f));
}

// ---------------------------------------------------------------------------
// Prep: f32 -> bf16 conversions + agh transpose + W3 pad (to 384 rows) + zero cnt.
// ---------------------------------------------------------------------------
#define PREP_TOTAL (2560000 + 163840 + 65536 + 262144 + 98304 + 10000)
__global__ void prep_kernel(const float* __restrict__ emb,
                            const float* __restrict__ W1,
                            const float* __restrict__ W2,
                            const float* __restrict__ agh,
                            const float* __restrict__ W3,
                            __hip_bfloat16* __restrict__ embB,
                            __hip_bfloat16* __restrict__ W1b,
                            __hip_bfloat16* __restrict__ W2b,
                            __hip_bfloat16* __restrict__ aghT,
                            __hip_bfloat16* __restrict__ W3b,
                            int* __restrict__ cnt) {
    int tid = blockIdx.x * blockDim.x + threadIdx.x;
    if (tid >= PREP_TOTAL) return;
    int j = tid;
    if (j < 2560000) { embB[j] = __float2bfloat16(emb[j]); return; }
    j -= 2560000;
    if (j < 163840) { W1b[j] = __float2bfloat16(W1[j]); return; }
    j -= 163840;
    if (j < 65536) { W2b[j] = __float2bfloat16(W2[j]); return; }
    j -= 65536;
    if (j < 262144) {
        int n = j >> 8, k = j & 255;
        aghT[j] = __float2bfloat16(agh[k * 1024 + n]);
        return;
    }
    j -= 262144;
    if (j < 98304) {   // W3b padded to 384x256
        int n = j >> 8;
        W3b[j] = (n < MLP_OUT) ? __float2bfloat16(W3[j]) : __float2bfloat16(0.f);
        return;
    }
    j -= 98304;
    cnt[j] = 0;
}

// ---------------------------------------------------------------------------
// Count-sort of pairs by destination atom: hist -> scan -> scatter_ids.
// ---------------------------------------------------------------------------
__global__ void hist_kernel(const int* __restrict__ idx_j, int* __restrict__ cnt) {
    int p = blockIdx.x * blockDim.x + threadIdx.x;
    if (p >= N_PAIRS) return;
    atomicAdd(&cnt[idx_j[p]], 1);
}

__global__ __launch_bounds__(1024) void scan_kernel(const int* __restrict__ cnt,
                                                    int* __restrict__ start,
                                                    int* __restrict__ cursor) {
    __shared__ int part[1024];
    int t = threadIdx.x;
    int base = t * 10;
    int pre[10];
    int sum = 0;
#pragma unroll
    for (int k = 0; k < 10; ++k) {
        int i = base + k;
        int v = (i < N_ATOMS) ? cnt[i] : 0;
        pre[k] = sum;
        sum += v;
    }
    part[t] = sum;
    __syncthreads();
    for (int off = 1; off < 1024; off <<= 1) {
        int v = (t >= off) ? part[t - off] : 0;
        __syncthreads();
        part[t] += v;
        __syncthreads();
    }
    int excl = (t == 0) ? 0 : part[t - 1];
#pragma unroll
    for (int k = 0; k < 10; ++k) {
        int i = base + k;
        if (i < N_ATOMS) {
            start[i]  = excl + pre[k];
            cursor[i] = excl + pre[k];
        }
    }
}

__global__ void scatter_ids_kernel(const int* __restrict__ idx_j,
                                   int* __restrict__ cursor,
                                   int* __restrict__ sorted) {
    int p = blockIdx.x * blockDim.x + threadIdx.x;
    if (p >= N_PAIRS) return;
    int i = idx_j[p];
    int pos = atomicAdd(&cursor[i], 1);
    sorted[pos] = p;
}

// ---------------------------------------------------------------------------
// bf16 MFMA GEMM: C[M,N] = A[M,K] @ B[N,K]^T, f32 accumulate.
// 256 thr = 2x2 waves; block tile 128x128; wave tile 64x64 (4x4 frags).
// 16 MFMA per 8 x 16B loads per K32 step. No LDS.
// MODE 0: store bf16   MODE 1: +bias, gelu, store bf16   MODE 2: +bias, remap
// N must be a multiple of 128 (pad B with zero rows).
// ---------------------------------------------------------------------------
template<int MODE, int M, int N, int K>
__global__ __launch_bounds__(256) void gemm_mfma(const short* __restrict__ A,
                                                 const short* __restrict__ B,
                                                 const float* __restrict__ bias,
                                                 void* __restrict__ Cout) {
    int lane = threadIdx.x & 63;
    int wave = threadIdx.x >> 6;
    int wr = wave >> 1, wc = wave & 1;
    int m0 = blockIdx.x * 128 + wr * 64;
    int n0 = blockIdx.y * 128 + wc * 64;
    int lr = lane & 15;
    int koff0 = (lane >> 4) * 8;

    f32x4 acc[4][4] = {};
    const short8 zero8 = {};

    const short* Arow[4];
    bool ok[4];
#pragma unroll
    for (int fm = 0; fm < 4; ++fm) {
        int row = m0 + fm * 16 + lr;
        ok[fm] = row < M;
        Arow[fm] = A + (long long)(ok[fm] ? row : 0) * K + koff0;
    }
    const short* Bb = B + (long long)(n0 + lr) * K + koff0;

#pragma unroll 2
    for (int ks = 0; ks < K; ks += 32) {
        short8 a[4], b[4];
#pragma unroll
        for (int fm = 0; fm < 4; ++fm)
            a[fm] = ok[fm] ? *(const short8*)(Arow[fm] + ks) : zero8;
#pragma unroll
        for (int fn = 0; fn < 4; ++fn)
            b[fn] = *(const short8*)(Bb + (long long)fn * 16 * K + ks);
#pragma unroll
        for (int fm = 0; fm < 4; ++fm)
#pragma unroll
            for (int fn = 0; fn < 4; ++fn)
                acc[fm][fn] = __builtin_amdgcn_mfma_f32_16x16x32_bf16(a[fm], b[fn],
                                                                      acc[fm][fn], 0, 0, 0);
    }

    // C/D layout: col = lane&15, row = (lane>>4)*4 + r
    float* outp = (float*)Cout;
    __hip_bfloat16* outb = (__hip_bfloat16*)Cout;
    int rbase = (lane >> 4) * 4;
#pragma unroll
    for (int fm = 0; fm < 4; ++fm) {
#pragma unroll
        for (int fn = 0; fn < 4; ++fn) {
            int col = n0 + fn * 16 + lr;
            if (MODE == 2 && col >= MLP_OUT) continue;
#pragma unroll
            for (int r = 0; r < 4; ++r) {
                int row = m0 + fm * 16 + rbase + r;
                if (row >= M) continue;
                float v = acc[fm][fn][r];
                if (MODE == 0) {
                    outb[(long long)row * N + col] = __float2bfloat16(v);
                } else if (MODE == 1) {
                    v += bias[col];
                    outb[(long long)row * N + col] = __float2bfloat16(gelu_exact(v));
                } else {
                    v += bias[col];
                    if (col == 0)      outp[2560000 + row] = v;
                    else if (col == 1) outp[2570000 + row] = v;
                    else               outp[(long long)row * 256 + (col - 2)] = v;
                }
            }
        }
    }
}

// ---------------------------------------------------------------------------
// Fused gather + build_combined. One block (256 thr) per atom.
// Phase A: segment-sum of the 64-float [gs(16)|gv(48)] pair rows via the
//          sorted index list (64 elems x 4 pair-strided partials, LDS reduce).
// Phase B: combined row = [emb*S | ||M x GV||_d | q*S | 0]  (bf16).
// ---------------------------------------------------------------------------
__global__ void build_combined(const int* __restrict__ sorted,
                               const int* __restrict__ start,
                               const int* __restrict__ cnt,
                               const float* __restrict__ gs,
                               const float* __restrict__ gv,
                               const float* __restrict__ emb,
                               const float* __restrict__ q,
                               const float* __restrict__ W_gs,
                               const __hip_bfloat16* __restrict__ Mmat,
                               __hip_bfloat16* __restrict__ combined) {
    __shared__ float sW[FDIM * 17];
    __shared__ float sAcc[4][64];
    __shared__ float sG[GDIM];
    __shared__ float sGV[48];
    int i = blockIdx.x;
    int t = threadIdx.x;

    for (int j = t; j < FDIM * GDIM; j += 256) {
        sW[(j >> 4) * 17 + (j & 15)] = W_gs[j];
    }

    // Phase A: gather
    int s = start[i];
    int c = cnt[i];
    int e = t & 63, sub = t >> 6;
    float a = 0.f;
    for (int j = sub; j < c; j += 4) {
        int p = sorted[s + j];
        a += (e < 16) ? gs[p * 16 + e] : gv[p * 48 + (e - 16)];
    }
    sAcc[sub][e] = a;
    __syncthreads();
    if (t < 64) {
        float v = sAcc[0][t] + sAcc[1][t] + sAcc[2][t] + sAcc[3][t];
        if (t < 16) sG[t] = v;
        else        sGV[t - 16] = v;
    }
    __syncthreads();

    // Phase B
    float S = 0.f;
#pragma unroll
    for (int g = 0; g < GDIM; ++g) S += sG[g] * sW[t * 17 + g];

    float ev = emb[(long long)i * FDIM + t];
    float qq = q[i];
    __hip_bfloat16* crow = combined + (long long)i * MLP_IN;
    crow[t]       = __float2bfloat16(ev * S);
    crow[320 + t] = __float2bfloat16(qq * S);

    if (t < HDIM) {
        float a0 = 0.f, a1 = 0.f, a2 = 0.f;
#pragma unroll
        for (int g = 0; g < GDIM; ++g) {
            float mg = __bfloat162float(Mmat[(long long)i * 1024 + g * 64 + t]);
            a0 += mg * sGV[0 * 16 + g];
            a1 += mg * sGV[1 * 16 + g];
            a2 += mg * sGV[2 * 16 + g];
        }
        crow[256 + t] = __float2bfloat16(sqrtf(a0 * a0 + a1 * a1 + a2 * a2));
        crow[576 + t] = __float2bfloat16(0.f);
    }
}

extern "C" void kernel_launch(void* const* d_in, const int* in_sizes, int n_in,
                              void* d_out, int out_size, void* d_ws, size_t ws_size,
                              hipStream_t stream) {
    const float* emb  = (const float*)d_in[0];
    const float* q    = (const float*)d_in[1];
    const int*   pidx = (const int*)d_in[2];
    const float* gs   = (const float*)d_in[3];
    const float* gv   = (const float*)d_in[4];
    const float* agh  = (const float*)d_in[5];
    const float* W_gs = (const float*)d_in[6];
    const float* W1   = (const float*)d_in[7];
    const float* b1   = (const float*)d_in[8];
    const float* W2   = (const float*)d_in[9];
    const float* b2   = (const float*)d_in[10];
    const float* W3   = (const float*)d_in[11];
    const float* b3   = (const float*)d_in[12];
    float* out = (float*)d_out;
    float* ws  = (float*)d_ws;

    // Workspace layout (float-slot offsets). h1b/h2b alias the dead Mmat region.
    // Peak footprint: 10,084,912 floats = 40.3 MB (42.9 MB proven safe in r5).
    int*   cnt    = (int*)(ws);                                // 10,000
    int*   startA = (int*)(ws + 10000);                        // 10,000
    int*   cursor = (int*)(ws + 20000);                        // 10,000
    int*   sorted = (int*)(ws + 30000);                        // 160,000
    __hip_bfloat16* Mmat = (__hip_bfloat16*)(ws + 190000);     // 10000x1024 bf16 (5,120,000 f)
    __hip_bfloat16* h1b  = (__hip_bfloat16*)(ws + 190000);     //   aliases Mmat[0:]
    __hip_bfloat16* h2b  = (__hip_bfloat16*)(ws + 1470000);    //   aliases Mmat[2.56M:]
    __hip_bfloat16* embB = (__hip_bfloat16*)(ws + 5310000);    // 10000x256 bf16
    __hip_bfloat16* aghT = (__hip_bfloat16*)(ws + 6590000);    // 1024x256 bf16
    __hip_bfloat16* W1b  = (__hip_bfloat16*)(ws + 6721072);    // 256x640 bf16
    __hip_bfloat16* W2b  = (__hip_bfloat16*)(ws + 6802992);    // 256x256 bf16
    __hip_bfloat16* W3b  = (__hip_bfloat16*)(ws + 6835760);    // 384x256 bf16 (padded)
    __hip_bfloat16* comb = (__hip_bfloat16*)(ws + 6884912);    // 10000x640 bf16
    // end: 10,084,912 floats

    const int* idx_j = pidx + N_PAIRS;

    {   // bf16 conversions + transposes + cnt zeroing
        int blocks = (PREP_TOTAL + 255) / 256;
        prep_kernel<<<blocks, 256, 0, stream>>>(emb, W1, W2, agh, W3,
                                                embB, W1b, W2b, aghT, W3b, cnt);
    }
    {   // count-sort pairs by atom
        int blocks = (N_PAIRS + 255) / 256;
        hist_kernel<<<blocks, 256, 0, stream>>>(idx_j, cnt);
        scan_kernel<<<1, 1024, 0, stream>>>(cnt, startA, cursor);
        scatter_ids_kernel<<<blocks, 256, 0, stream>>>(idx_j, cursor, sorted);
    }
    {   // Mmat = embB @ aghT^T : (10000x256)@(256x1024) -> bf16
        dim3 grid((N_ATOMS + 127) / 128, 1024 / 128);
        gemm_mfma<0, N_ATOMS, 1024, 256><<<grid, 256, 0, stream>>>(
            (const short*)embB, (const short*)aghT, nullptr, Mmat);
    }
    // fused gather + combined-builder
    build_combined<<<N_ATOMS, 256, 0, stream>>>(sorted, startA, cnt, gs, gv,
                                                emb, q, W_gs, Mmat, comb);
    {   // MLP1 + MLP2 (h1b/h2b live in the now-dead Mmat region)
        dim3 grid((N_ATOMS + 127) / 128, HIDDIM / 128);
        gemm_mfma<1, N_ATOMS, HIDDIM, MLP_IN><<<grid, 256, 0, stream>>>(
            (const short*)comb, (const short*)W1b, b1, h1b);
        gemm_mfma<1, N_ATOMS, HIDDIM, HIDDIM><<<grid, 256, 0, stream>>>(
            (const short*)h1b, (const short*)W2b, b2, h2b);
    }
    {   // MLP3 + remap (N padded to 384)
        dim3 grid((N_ATOMS + 127) / 128, 384 / 128);
        gemm_mfma<2, N_ATOMS, 384, HIDDIM><<<grid, 256, 0, stream>>>(
            (const short*)h2b, (const short*)W3b, b3, out);
    }
}

// Round 7
// 178.920 us; speedup vs baseline: 1.1053x; 1.1053x over previous
//
#include <hip/hip_runtime.h>
#include <hip/hip_bf16.h>
#include <math.h>

#define N_ATOMS 10000
#define N_PAIRS 160000
#define FDIM 256
#define GDIM 16
#define HDIM 64
#define HIDDIM 256
#define MLP_IN 640
#define MLP_OUT 258

typedef __attribute__((ext_vector_type(8))) short short8;
typedef __attribute__((ext_vector_type(4))) float f32x4;

__device__ __forceinline__ float gelu_exact(float x) {
    return 0.5f * x * (1.0f + erff(x * 0.70710678118654752f));
}
__device__ __forceinline__ short bf16bits(float x) {
    __hip_bfloat16 h = __float2bfloat16(x);
    return *reinterpret_cast<short*>(&h);
}

// ---------------------------------------------------------------------------
// Prep: emb->bf16 vectorized (8/thread), then scalar regions:
//   W1b(163840) W2b(65536) aghT(262144, transpose) W3b(81920, pad to 320) cnt(10000)
// ---------------------------------------------------------------------------
#define PREP_VEC 320000
#define PREP_TOTAL (PREP_VEC + 163840 + 65536 + 262144 + 81920 + 10000)
__global__ void prep_kernel(const float* __restrict__ emb,
                            const float* __restrict__ W1,
                            const float* __restrict__ W2,
                            const float* __restrict__ agh,
                            const float* __restrict__ W3,
                            __hip_bfloat16* __restrict__ embB,
                            __hip_bfloat16* __restrict__ W1b,
                            __hip_bfloat16* __restrict__ W2b,
                            __hip_bfloat16* __restrict__ aghT,
                            __hip_bfloat16* __restrict__ W3b,
                            int* __restrict__ cnt) {
    int tid = blockIdx.x * blockDim.x + threadIdx.x;
    if (tid >= PREP_TOTAL) return;
    int j = tid;
    if (j < PREP_VEC) {   // embB: 8 elems per thread, vectorized
        int base = j * 8;
        f32x4 v0 = *(const f32x4*)(emb + base);
        f32x4 v1 = *(const f32x4*)(emb + base + 4);
        short8 o;
        o[0] = bf16bits(v0[0]); o[1] = bf16bits(v0[1]);
        o[2] = bf16bits(v0[2]); o[3] = bf16bits(v0[3]);
        o[4] = bf16bits(v1[0]); o[5] = bf16bits(v1[1]);
        o[6] = bf16bits(v1[2]); o[7] = bf16bits(v1[3]);
        *(short8*)((short*)embB + base) = o;
        return;
    }
    j -= PREP_VEC;
    if (j < 163840) { W1b[j] = __float2bfloat16(W1[j]); return; }
    j -= 163840;
    if (j < 65536) { W2b[j] = __float2bfloat16(W2[j]); return; }
    j -= 65536;
    if (j < 262144) {
        int n = j >> 8, k = j & 255;
        aghT[j] = __float2bfloat16(agh[k * 1024 + n]);
        return;
    }
    j -= 262144;
    if (j < 81920) {   // W3b padded to 320x256
        int n = j >> 8;
        W3b[j] = (n < MLP_OUT) ? __float2bfloat16(W3[j]) : __float2bfloat16(0.f);
        return;
    }
    j -= 81920;
    cnt[j] = 0;
}

// ---------------------------------------------------------------------------
// Count-sort of pairs by destination atom: hist -> scan -> scatter_ids.
// ---------------------------------------------------------------------------
__global__ void hist_kernel(const int* __restrict__ idx_j, int* __restrict__ cnt) {
    int p = blockIdx.x * blockDim.x + threadIdx.x;
    if (p >= N_PAIRS) return;
    atomicAdd(&cnt[idx_j[p]], 1);
}

__global__ __launch_bounds__(1024) void scan_kernel(const int* __restrict__ cnt,
                                                    int* __restrict__ start,
                                                    int* __restrict__ cursor) {
    __shared__ int part[1024];
    int t = threadIdx.x;
    int base = t * 10;
    int pre[10];
    int sum = 0;
#pragma unroll
    for (int k = 0; k < 10; ++k) {
        int i = base + k;
        int v = (i < N_ATOMS) ? cnt[i] : 0;
        pre[k] = sum;
        sum += v;
    }
    part[t] = sum;
    __syncthreads();
    for (int off = 1; off < 1024; off <<= 1) {
        int v = (t >= off) ? part[t - off] : 0;
        __syncthreads();
        part[t] += v;
        __syncthreads();
    }
    int excl = (t == 0) ? 0 : part[t - 1];
#pragma unroll
    for (int k = 0; k < 10; ++k) {
        int i = base + k;
        if (i < N_ATOMS) {
            start[i]  = excl + pre[k];
            cursor[i] = excl + pre[k];
        }
    }
}

__global__ void scatter_ids_kernel(const int* __restrict__ idx_j,
                                   int* __restrict__ cursor,
                                   int* __restrict__ sorted) {
    int p = blockIdx.x * blockDim.x + threadIdx.x;
    if (p >= N_PAIRS) return;
    int i = idx_j[p];
    int pos = atomicAdd(&cursor[i], 1);
    sorted[pos] = p;
}

// Gather: 16 lanes per atom, float4 per lane over [gs(16) | gv(48)].
__global__ void gather_kernel(const int* __restrict__ sorted,
                              const int* __restrict__ start,
                              const int* __restrict__ cnt,
                              const float* __restrict__ gs,
                              const float* __restrict__ gv,
                              float* __restrict__ Gs_sum,
                              float* __restrict__ GV_sum) {
    int t = threadIdx.x;
    int grp = t >> 4;
    int l = t & 15;
    int atom = blockIdx.x * 16 + grp;
    if (atom >= N_ATOMS) return;
    int s = start[atom];
    int c = cnt[atom];
    const float* base;
    long long stride;
    if (l < 4) { base = gs + l * 4;        stride = 16; }
    else       { base = gv + (l - 4) * 4;  stride = 48; }
    f32x4 acc = {0.f, 0.f, 0.f, 0.f};
    int j = 0;
    for (; j + 1 < c; j += 2) {
        int p0 = sorted[s + j];
        int p1 = sorted[s + j + 1];
        f32x4 v0 = *(const f32x4*)(base + p0 * stride);
        f32x4 v1 = *(const f32x4*)(base + p1 * stride);
        acc += v0;
        acc += v1;
    }
    if (j < c) {
        int p0 = sorted[s + j];
        acc += *(const f32x4*)(base + p0 * stride);
    }
    float* dst = (l < 4) ? (Gs_sum + atom * 16 + l * 4)
                         : (GV_sum + atom * 48 + (l - 4) * 4);
    *(f32x4*)dst = acc;
}

// ---------------------------------------------------------------------------
// bf16 MFMA GEMM: C[M,N] = A[M,K] @ B[N,K]^T, f32 accumulate.
// 64-thread blocks, one wave, 64x64 tile (4x4 frags): maximizes block count
// for these skinny GEMMs (grid starvation was the r6 bottleneck).
// 16 MFMA per 8 x 16B loads per K32 step. No LDS.
// MODE 0: store bf16   MODE 1: +bias, gelu, store bf16   MODE 2: +bias, remap
// ---------------------------------------------------------------------------
template<int MODE, int M, int N, int K>
__global__ __launch_bounds__(64) void gemm_mfma(const short* __restrict__ A,
                                                const short* __restrict__ B,
                                                const float* __restrict__ bias,
                                                void* __restrict__ Cout) {
    int lane = threadIdx.x;
    int m0 = blockIdx.x * 64;
    int n0 = blockIdx.y * 64;
    int lr = lane & 15;
    int koff0 = (lane >> 4) * 8;

    f32x4 acc[4][4] = {};
    const short8 zero8 = {};

    const short* Arow[4];
    bool ok[4];
#pragma unroll
    for (int fm = 0; fm < 4; ++fm) {
        int row = m0 + fm * 16 + lr;
        ok[fm] = row < M;
        Arow[fm] = A + (long long)(ok[fm] ? row : 0) * K + koff0;
    }
    const short* Bb = B + (long long)(n0 + lr) * K + koff0;

#pragma unroll 2
    for (int ks = 0; ks < K; ks += 32) {
        short8 a[4], b[4];
#pragma unroll
        for (int fm = 0; fm < 4; ++fm)
            a[fm] = ok[fm] ? *(const short8*)(Arow[fm] + ks) : zero8;
#pragma unroll
        for (int fn = 0; fn < 4; ++fn)
            b[fn] = *(const short8*)(Bb + (long long)fn * 16 * K + ks);
#pragma unroll
        for (int fm = 0; fm < 4; ++fm)
#pragma unroll
            for (int fn = 0; fn < 4; ++fn)
                acc[fm][fn] = __builtin_amdgcn_mfma_f32_16x16x32_bf16(a[fm], b[fn],
                                                                      acc[fm][fn], 0, 0, 0);
    }

    // C/D layout: col = lane&15, row = (lane>>4)*4 + r
    float* outp = (float*)Cout;
    __hip_bfloat16* outb = (__hip_bfloat16*)Cout;
    int rbase = (lane >> 4) * 4;
#pragma unroll
    for (int fm = 0; fm < 4; ++fm) {
#pragma unroll
        for (int fn = 0; fn < 4; ++fn) {
            int col = n0 + fn * 16 + lr;
            if (MODE == 2 && col >= MLP_OUT) continue;
#pragma unroll
            for (int r = 0; r < 4; ++r) {
                int row = m0 + fm * 16 + rbase + r;
                if (row >= M) continue;
                float v = acc[fm][fn][r];
                if (MODE == 0) {
                    outb[(long long)row * N + col] = __float2bfloat16(v);
                } else if (MODE == 1) {
                    v += bias[col];
                    outb[(long long)row * N + col] = __float2bfloat16(gelu_exact(v));
                } else {
                    v += bias[col];
                    if (col == 0)      outp[2560000 + row] = v;
                    else if (col == 1) outp[2570000 + row] = v;
                    else               outp[(long long)row * 256 + (col - 2)] = v;
                }
            }
        }
    }
}

// ---------------------------------------------------------------------------
// build_combined v2: 16 atoms per 256-thread block (grid 625).
// W_gs staged ONCE per block; all loops fully parallel; conflict-free LDS.
// combined row = [emb*S | ||M x GV||_d | q*S | 0]  (bf16)
// ---------------------------------------------------------------------------
__global__ __launch_bounds__(256) void build_combined(
        const float* __restrict__ Gs_sum,
        const float* __restrict__ GV_sum,
        const float* __restrict__ emb,
        const float* __restrict__ q,
        const float* __restrict__ W_gs,
        const __hip_bfloat16* __restrict__ Mmat,
        __hip_bfloat16* __restrict__ combined) {
    __shared__ float sW[FDIM * 17];
    __shared__ float sG[16][GDIM];
    __shared__ float sGV[16][48];
    int i0 = blockIdx.x * 16;
    int t = threadIdx.x;

    for (int j = t; j < FDIM * GDIM; j += 256)
        sW[(j >> 4) * 17 + (j & 15)] = W_gs[j];
    { int a = t >> 4, g = t & 15; sG[a][g] = Gs_sum[(i0 + a) * 16 + g]; }
    for (int j = t; j < 16 * 48; j += 256) {
        int a = j / 48, e = j - a * 48;
        sGV[a][e] = GV_sum[(i0 + a) * 48 + e];
    }
    __syncthreads();

    float wreg[GDIM];
#pragma unroll
    for (int g = 0; g < GDIM; ++g) wreg[g] = sW[t * 17 + g];

    // radial_emb / radial_q for 16 atoms (thread t owns feature f = t)
#pragma unroll 4
    for (int a = 0; a < 16; ++a) {
        int i = i0 + a;
        float S = 0.f;
#pragma unroll
        for (int g = 0; g < GDIM; ++g) S += sG[a][g] * wreg[g];
        float ev = emb[(long long)i * FDIM + t];
        float qq = q[i];
        __hip_bfloat16* crow = combined + (long long)i * MLP_IN;
        crow[t]       = __float2bfloat16(ev * S);
        crow[320 + t] = __float2bfloat16(qq * S);
    }

    // vector_emb: wave w handles atoms w, w+4, w+8, w+12; lanes cover h=0..63
#pragma unroll
    for (int r = 0; r < 4; ++r) {
        int a = (t >> 6) + r * 4;
        int h = t & 63;
        int i = i0 + a;
        float a0 = 0.f, a1 = 0.f, a2 = 0.f;
#pragma unroll
        for (int g = 0; g < GDIM; ++g) {
            float mg = __bfloat162float(Mmat[(long long)i * 1024 + g * 64 + h]);
            a0 += mg * sGV[a][g];
            a1 += mg * sGV[a][16 + g];
            a2 += mg * sGV[a][32 + g];
        }
        __hip_bfloat16* crow = combined + (long long)i * MLP_IN;
        crow[256 + h] = __float2bfloat16(sqrtf(a0 * a0 + a1 * a1 + a2 * a2));
        crow[576 + h] = __float2bfloat16(0.f);
    }
}

extern "C" void kernel_launch(void* const* d_in, const int* in_sizes, int n_in,
                              void* d_out, int out_size, void* d_ws, size_t ws_size,
                              hipStream_t stream) {
    const float* emb  = (const float*)d_in[0];
    const float* q    = (const float*)d_in[1];
    const int*   pidx = (const int*)d_in[2];
    const float* gs   = (const float*)d_in[3];
    const float* gv   = (const float*)d_in[4];
    const float* agh  = (const float*)d_in[5];
    const float* W_gs = (const float*)d_in[6];
    const float* W1   = (const float*)d_in[7];
    const float* b1   = (const float*)d_in[8];
    const float* W2   = (const float*)d_in[9];
    const float* b2   = (const float*)d_in[10];
    const float* W3   = (const float*)d_in[11];
    const float* b3   = (const float*)d_in[12];
    float* out = (float*)d_out;
    float* ws  = (float*)d_ws;

    // Workspace (float-slot offsets). h1b/h2b alias the dead Mmat region.
    // Peak: 10,724,912 floats = 42.9 MB (r5 proved 42.9 MB safe; r4's 53.1 failed).
    float* Gs_sum = ws;                                        // 160,000 f
    float* GV_sum = ws + 160000;                               // 480,000 f
    int*   cnt    = (int*)(ws + 640000);                       // 10,000
    int*   startA = (int*)(ws + 650000);                       // 10,000
    int*   cursor = (int*)(ws + 660000);                       // 10,000
    int*   sorted = (int*)(ws + 670000);                       // 160,000
    __hip_bfloat16* Mmat = (__hip_bfloat16*)(ws + 830000);     // 10000x1024 bf16 (5,120,000 f)
    __hip_bfloat16* h1b  = (__hip_bfloat16*)(ws + 830000);     //   aliases Mmat[0:]
    __hip_bfloat16* h2b  = (__hip_bfloat16*)(ws + 2110000);    //   aliases Mmat[2.56M:]
    __hip_bfloat16* embB = (__hip_bfloat16*)(ws + 5950000);    // 10000x256 bf16
    __hip_bfloat16* aghT = (__hip_bfloat16*)(ws + 7230000);    // 1024x256 bf16
    __hip_bfloat16* W1b  = (__hip_bfloat16*)(ws + 7361072);    // 256x640 bf16
    __hip_bfloat16* W2b  = (__hip_bfloat16*)(ws + 7442992);    // 256x256 bf16
    __hip_bfloat16* W3b  = (__hip_bfloat16*)(ws + 7475760);    // 320x256 bf16 (padded)
    __hip_bfloat16* comb = (__hip_bfloat16*)(ws + 7524912);    // 10000x640 bf16
    // end: 10,724,912 floats

    const int* idx_j = pidx + N_PAIRS;

    {   // conversions + transposes + cnt zeroing
        int blocks = (PREP_TOTAL + 255) / 256;
        prep_kernel<<<blocks, 256, 0, stream>>>(emb, W1, W2, agh, W3,
                                                embB, W1b, W2b, aghT, W3b, cnt);
    }
    {   // count-sort pairs by atom
        int blocks = (N_PAIRS + 255) / 256;
        hist_kernel<<<blocks, 256, 0, stream>>>(idx_j, cnt);
        scan_kernel<<<1, 1024, 0, stream>>>(cnt, startA, cursor);
        scatter_ids_kernel<<<blocks, 256, 0, stream>>>(idx_j, cursor, sorted);
    }
    {   // Mmat = embB @ aghT^T : (10000x256)@(256x1024) -> bf16
        dim3 grid((N_ATOMS + 63) / 64, 1024 / 64);
        gemm_mfma<0, N_ATOMS, 1024, 256><<<grid, 64, 0, stream>>>(
            (const short*)embB, (const short*)aghT, nullptr, Mmat);
    }
    {   // segment-sums via gather
        int blocks = (N_ATOMS + 15) / 16;
        gather_kernel<<<blocks, 256, 0, stream>>>(sorted, startA, cnt, gs, gv,
                                                  Gs_sum, GV_sum);
    }
    // combined builder (16 atoms/block)
    build_combined<<<(N_ATOMS + 15) / 16, 256, 0, stream>>>(
        Gs_sum, GV_sum, emb, q, W_gs, Mmat, comb);
    {   // MLP1 + MLP2 (h1b/h2b live in the now-dead Mmat region)
        dim3 grid((N_ATOMS + 63) / 64, HIDDIM / 64);
        gemm_mfma<1, N_ATOMS, HIDDIM, MLP_IN><<<grid, 64, 0, stream>>>(
            (const short*)comb, (const short*)W1b, b1, h1b);
        gemm_mfma<1, N_ATOMS, HIDDIM, HIDDIM><<<grid, 64, 0, stream>>>(
            (const short*)h1b, (const short*)W2b, b2, h2b);
    }
    {   // MLP3 + remap (N padded to 320; cols >= 258 skipped at store)
        dim3 grid((N_ATOMS + 63) / 64, 320 / 64);
        gemm_mfma<2, N_ATOMS, 320, HIDDIM><<<grid, 64, 0, stream>>>(
            (const short*)h2b, (const short*)W3b, b3, out);
    }
}

// Round 8
// 154.254 us; speedup vs baseline: 1.2820x; 1.1599x over previous
//
#include <hip/hip_runtime.h>
#include <hip/hip_bf16.h>
#include <math.h>

#define N_ATOMS 10000
#define N_PAIRS 160000
#define FDIM 256
#define GDIM 16
#define HDIM 64
#define HIDDIM 256
#define MLP_IN 640
#define MLP_OUT 258

typedef __attribute__((ext_vector_type(8))) short short8;
typedef __attribute__((ext_vector_type(4))) float f32x4;

__device__ __forceinline__ float gelu_exact(float x) {
    return 0.5f * x * (1.0f + erff(x * 0.70710678118654752f));
}
__device__ __forceinline__ short bf16bits(float x) {
    __hip_bfloat16 h = __float2bfloat16(x);
    return *reinterpret_cast<short*>(&h);
}

// ---------------------------------------------------------------------------
// Prep: emb->bf16 vectorized (8/thread), then scalar regions:
//   W1b(163840) W2b(65536) aghT(262144, transpose) W3b(81920, pad to 320) cnt(10000)
// ---------------------------------------------------------------------------
#define PREP_VEC 320000
#define PREP_TOTAL (PREP_VEC + 163840 + 65536 + 262144 + 81920 + 10000)
__global__ void prep_kernel(const float* __restrict__ emb,
                            const float* __restrict__ W1,
                            const float* __restrict__ W2,
                            const float* __restrict__ agh,
                            const float* __restrict__ W3,
                            __hip_bfloat16* __restrict__ embB,
                            __hip_bfloat16* __restrict__ W1b,
                            __hip_bfloat16* __restrict__ W2b,
                            __hip_bfloat16* __restrict__ aghT,
                            __hip_bfloat16* __restrict__ W3b,
                            int* __restrict__ cnt) {
    int tid = blockIdx.x * blockDim.x + threadIdx.x;
    if (tid >= PREP_TOTAL) return;
    int j = tid;
    if (j < PREP_VEC) {   // embB: 8 elems per thread, vectorized
        int base = j * 8;
        f32x4 v0 = *(const f32x4*)(emb + base);
        f32x4 v1 = *(const f32x4*)(emb + base + 4);
        short8 o;
        o[0] = bf16bits(v0[0]); o[1] = bf16bits(v0[1]);
        o[2] = bf16bits(v0[2]); o[3] = bf16bits(v0[3]);
        o[4] = bf16bits(v1[0]); o[5] = bf16bits(v1[1]);
        o[6] = bf16bits(v1[2]); o[7] = bf16bits(v1[3]);
        *(short8*)((short*)embB + base) = o;
        return;
    }
    j -= PREP_VEC;
    if (j < 163840) { W1b[j] = __float2bfloat16(W1[j]); return; }
    j -= 163840;
    if (j < 65536) { W2b[j] = __float2bfloat16(W2[j]); return; }
    j -= 65536;
    if (j < 262144) {
        int n = j >> 8, k = j & 255;
        aghT[j] = __float2bfloat16(agh[k * 1024 + n]);
        return;
    }
    j -= 262144;
    if (j < 81920) {   // W3b padded to 320x256
        int n = j >> 8;
        W3b[j] = (n < MLP_OUT) ? __float2bfloat16(W3[j]) : __float2bfloat16(0.f);
        return;
    }
    j -= 81920;
    cnt[j] = 0;
}

// ---------------------------------------------------------------------------
// Count-sort of pairs by destination atom: hist -> scan -> scatter_ids.
// ---------------------------------------------------------------------------
__global__ void hist_kernel(const int* __restrict__ idx_j, int* __restrict__ cnt) {
    int p = blockIdx.x * blockDim.x + threadIdx.x;
    if (p >= N_PAIRS) return;
    atomicAdd(&cnt[idx_j[p]], 1);
}

__global__ __launch_bounds__(1024) void scan_kernel(const int* __restrict__ cnt,
                                                    int* __restrict__ start,
                                                    int* __restrict__ cursor) {
    __shared__ int part[1024];
    int t = threadIdx.x;
    int base = t * 10;
    int pre[10];
    int sum = 0;
#pragma unroll
    for (int k = 0; k < 10; ++k) {
        int i = base + k;
        int v = (i < N_ATOMS) ? cnt[i] : 0;
        pre[k] = sum;
        sum += v;
    }
    part[t] = sum;
    __syncthreads();
    for (int off = 1; off < 1024; off <<= 1) {
        int v = (t >= off) ? part[t - off] : 0;
        __syncthreads();
        part[t] += v;
        __syncthreads();
    }
    int excl = (t == 0) ? 0 : part[t - 1];
#pragma unroll
    for (int k = 0; k < 10; ++k) {
        int i = base + k;
        if (i < N_ATOMS) {
            start[i]  = excl + pre[k];
            cursor[i] = excl + pre[k];
        }
    }
}

__global__ void scatter_ids_kernel(const int* __restrict__ idx_j,
                                   int* __restrict__ cursor,
                                   int* __restrict__ sorted) {
    int p = blockIdx.x * blockDim.x + threadIdx.x;
    if (p >= N_PAIRS) return;
    int i = idx_j[p];
    int pos = atomicAdd(&cursor[i], 1);
    sorted[pos] = p;
}

// ---------------------------------------------------------------------------
// bf16 MFMA GEMM (Mmat only): C[M,N] = A[M,K] @ B[N,K]^T, bf16 out.
// 64-thread blocks, one wave, 64x64 tile (4x4 frags). No LDS.
// ---------------------------------------------------------------------------
template<int M, int N, int K>
__global__ __launch_bounds__(64) void gemm_mfma(const short* __restrict__ A,
                                                const short* __restrict__ B,
                                                __hip_bfloat16* __restrict__ Cout) {
    int lane = threadIdx.x;
    int m0 = blockIdx.x * 64;
    int n0 = blockIdx.y * 64;
    int lr = lane & 15;
    int koff0 = (lane >> 4) * 8;

    f32x4 acc[4][4] = {};
    const short8 zero8 = {};

    const short* Arow[4];
    bool ok[4];
#pragma unroll
    for (int fm = 0; fm < 4; ++fm) {
        int row = m0 + fm * 16 + lr;
        ok[fm] = row < M;
        Arow[fm] = A + (long long)(ok[fm] ? row : 0) * K + koff0;
    }
    const short* Bb = B + (long long)(n0 + lr) * K + koff0;

#pragma unroll 2
    for (int ks = 0; ks < K; ks += 32) {
        short8 a[4], b[4];
#pragma unroll
        for (int fm = 0; fm < 4; ++fm)
            a[fm] = ok[fm] ? *(const short8*)(Arow[fm] + ks) : zero8;
#pragma unroll
        for (int fn = 0; fn < 4; ++fn)
            b[fn] = *(const short8*)(Bb + (long long)fn * 16 * K + ks);
#pragma unroll
        for (int fm = 0; fm < 4; ++fm)
#pragma unroll
            for (int fn = 0; fn < 4; ++fn)
                acc[fm][fn] = __builtin_amdgcn_mfma_f32_16x16x32_bf16(a[fm], b[fn],
                                                                      acc[fm][fn], 0, 0, 0);
    }

    int rbase = (lane >> 4) * 4;
#pragma unroll
    for (int fm = 0; fm < 4; ++fm) {
#pragma unroll
        for (int fn = 0; fn < 4; ++fn) {
            int col = n0 + fn * 16 + lr;
#pragma unroll
            for (int r = 0; r < 4; ++r) {
                int row = m0 + fm * 16 + rbase + r;
                if (row >= M) continue;
                Cout[(long long)row * N + col] = __float2bfloat16(acc[fm][fn][r]);
            }
        }
    }
}

// ---------------------------------------------------------------------------
// Fused gather + build_combined: 16 atoms per 256-thread block (grid 625).
// Phase A: per-atom segment-sum of [gs(16)|gv(48)] via sorted ids (16 lanes/atom,
//          float4 per lane) -> LDS.  Phase B: combined row (bf16).
// ---------------------------------------------------------------------------
__global__ __launch_bounds__(256) void gather_build(
        const int* __restrict__ sorted,
        const int* __restrict__ start,
        const int* __restrict__ cnt,
        const float* __restrict__ gs,
        const float* __restrict__ gv,
        const float* __restrict__ emb,
        const float* __restrict__ q,
        const float* __restrict__ W_gs,
        const __hip_bfloat16* __restrict__ Mmat,
        __hip_bfloat16* __restrict__ combined) {
    __shared__ float sW[FDIM * 17];
    __shared__ float sG[16][GDIM];
    __shared__ float sGV[16][48];
    int i0 = blockIdx.x * 16;
    int t = threadIdx.x;

    for (int j = t; j < FDIM * GDIM; j += 256)
        sW[(j >> 4) * 17 + (j & 15)] = W_gs[j];

    // Phase A: gather (16 lanes per atom)
    {
        int grp = t >> 4, l = t & 15;
        int atom = i0 + grp;
        int s = start[atom], c = cnt[atom];
        const float* base;
        long long stride;
        if (l < 4) { base = gs + l * 4;        stride = 16; }
        else       { base = gv + (l - 4) * 4;  stride = 48; }
        f32x4 acc = {0.f, 0.f, 0.f, 0.f};
        int j = 0;
        for (; j + 1 < c; j += 2) {
            int p0 = sorted[s + j];
            int p1 = sorted[s + j + 1];
            acc += *(const f32x4*)(base + p0 * stride);
            acc += *(const f32x4*)(base + p1 * stride);
        }
        if (j < c) {
            int p0 = sorted[s + j];
            acc += *(const f32x4*)(base + p0 * stride);
        }
        if (l < 4) *(f32x4*)&sG[grp][l * 4] = acc;
        else       *(f32x4*)&sGV[grp][(l - 4) * 4] = acc;
    }
    __syncthreads();

    float wreg[GDIM];
#pragma unroll
    for (int g = 0; g < GDIM; ++g) wreg[g] = sW[t * 17 + g];

    // radial_emb / radial_q (thread t owns feature f = t)
#pragma unroll 4
    for (int a = 0; a < 16; ++a) {
        int i = i0 + a;
        float S = 0.f;
#pragma unroll
        for (int g = 0; g < GDIM; ++g) S += sG[a][g] * wreg[g];
        float ev = emb[(long long)i * FDIM + t];
        float qq = q[i];
        __hip_bfloat16* crow = combined + (long long)i * MLP_IN;
        crow[t]       = __float2bfloat16(ev * S);
        crow[320 + t] = __float2bfloat16(qq * S);
    }

    // vector_emb: wave w handles atoms w, w+4, w+8, w+12; lanes cover h=0..63
#pragma unroll
    for (int r = 0; r < 4; ++r) {
        int a = (t >> 6) + r * 4;
        int h = t & 63;
        int i = i0 + a;
        float a0 = 0.f, a1 = 0.f, a2 = 0.f;
#pragma unroll
        for (int g = 0; g < GDIM; ++g) {
            float mg = __bfloat162float(Mmat[(long long)i * 1024 + g * 64 + h]);
            a0 += mg * sGV[a][g];
            a1 += mg * sGV[a][16 + g];
            a2 += mg * sGV[a][32 + g];
        }
        __hip_bfloat16* crow = combined + (long long)i * MLP_IN;
        crow[256 + h] = __float2bfloat16(sqrtf(a0 * a0 + a1 * a1 + a2 * a2));
        crow[576 + h] = __float2bfloat16(0.f);
    }
}

// ---------------------------------------------------------------------------
// Fused MLP: out = (h2 @ W3^T + b3), h2 = gelu(h1 @ W2^T + b2),
//            h1 = gelu(comb @ W1^T + b1).
// 16 atoms per 256-thread block (grid 625, 2.4 blocks/CU). h1/h2 in LDS
// (padded stride 264 -> 2-way conflicts only). Wave w owns output cols
// [64w,64w+64) in phases 1-2 and [80w,80w+80) in phase 3 (N3 padded to 320).
// 10000 % 16 == 0 -> no row guards except final store.
// ---------------------------------------------------------------------------
__global__ __launch_bounds__(256) void mlp_fused(
        const short* __restrict__ comb,
        const short* __restrict__ W1b,
        const short* __restrict__ W2b,
        const short* __restrict__ W3b,
        const float* __restrict__ b1,
        const float* __restrict__ b2,
        const float* __restrict__ b3,
        float* __restrict__ outp) {
    __shared__ short h1s[16][264];
    __shared__ short h2s[16][264];
    int lane = threadIdx.x & 63;
    int wave = threadIdx.x >> 6;
    int m0 = blockIdx.x * 16;
    int lr = lane & 15;
    int ko = (lane >> 4) * 8;
    int rbase = (lane >> 4) * 4;

    const short* Arow = comb + (long long)(m0 + lr) * MLP_IN + ko;

    // Phase 1: h1 = gelu(comb @ W1^T + b1)
    {
        f32x4 acc[4] = {};
        const short* Bb = W1b + (long long)(wave * 64 + lr) * MLP_IN + ko;
#pragma unroll 4
        for (int ks = 0; ks < MLP_IN; ks += 32) {
            short8 a = *(const short8*)(Arow + ks);
            short8 b[4];
#pragma unroll
            for (int fn = 0; fn < 4; ++fn)
                b[fn] = *(const short8*)(Bb + (long long)fn * 16 * MLP_IN + ks);
#pragma unroll
            for (int fn = 0; fn < 4; ++fn)
                acc[fn] = __builtin_amdgcn_mfma_f32_16x16x32_bf16(a, b[fn], acc[fn], 0, 0, 0);
        }
#pragma unroll
        for (int fn = 0; fn < 4; ++fn) {
            int col = wave * 64 + fn * 16 + lr;
            float bias = b1[col];
#pragma unroll
            for (int r = 0; r < 4; ++r)
                h1s[rbase + r][col] = bf16bits(gelu_exact(acc[fn][r] + bias));
        }
    }
    __syncthreads();

    // Phase 2: h2 = gelu(h1 @ W2^T + b2)
    {
        f32x4 acc[4] = {};
        const short* Bb = W2b + (long long)(wave * 64 + lr) * HIDDIM + ko;
#pragma unroll
        for (int ks = 0; ks < HIDDIM; ks += 32) {
            short8 a = *(const short8*)(&h1s[lr][ko + ks]);
            short8 b[4];
#pragma unroll
            for (int fn = 0; fn < 4; ++fn)
                b[fn] = *(const short8*)(Bb + (long long)fn * 16 * HIDDIM + ks);
#pragma unroll
            for (int fn = 0; fn < 4; ++fn)
                acc[fn] = __builtin_amdgcn_mfma_f32_16x16x32_bf16(a, b[fn], acc[fn], 0, 0, 0);
        }
#pragma unroll
        for (int fn = 0; fn < 4; ++fn) {
            int col = wave * 64 + fn * 16 + lr;
            float bias = b2[col];
#pragma unroll
            for (int r = 0; r < 4; ++r)
                h2s[rbase + r][col] = bf16bits(gelu_exact(acc[fn][r] + bias));
        }
    }
    __syncthreads();

    // Phase 3: out = h2 @ W3^T + b3, remap (delta_a | delta_q | f)
    {
        f32x4 acc[5] = {};
        const short* Bb = W3b + (long long)(wave * 80 + lr) * HIDDIM + ko;
#pragma unroll
        for (int ks = 0; ks < HIDDIM; ks += 32) {
            short8 a = *(const short8*)(&h2s[lr][ko + ks]);
            short8 b[5];
#pragma unroll
            for (int fn = 0; fn < 5; ++fn)
                b[fn] = *(const short8*)(Bb + (long long)fn * 16 * HIDDIM + ks);
#pragma unroll
            for (int fn = 0; fn < 5; ++fn)
                acc[fn] = __builtin_amdgcn_mfma_f32_16x16x32_bf16(a, b[fn], acc[fn], 0, 0, 0);
        }
#pragma unroll
        for (int fn = 0; fn < 5; ++fn) {
            int col = wave * 80 + fn * 16 + lr;
            if (col >= MLP_OUT) continue;
            float bias = b3[col];
#pragma unroll
            for (int r = 0; r < 4; ++r) {
                int row = m0 + rbase + r;
                float v = acc[fn][r] + bias;
                if (col == 0)      outp[2560000 + row] = v;
                else if (col == 1) outp[2570000 + row] = v;
                else               outp[(long long)row * 256 + (col - 2)] = v;
            }
        }
    }
}

extern "C" void kernel_launch(void* const* d_in, const int* in_sizes, int n_in,
                              void* d_out, int out_size, void* d_ws, size_t ws_size,
                              hipStream_t stream) {
    const float* emb  = (const float*)d_in[0];
    const float* q    = (const float*)d_in[1];
    const int*   pidx = (const int*)d_in[2];
    const float* gs   = (const float*)d_in[3];
    const float* gv   = (const float*)d_in[4];
    const float* agh  = (const float*)d_in[5];
    const float* W_gs = (const float*)d_in[6];
    const float* W1   = (const float*)d_in[7];
    const float* b1   = (const float*)d_in[8];
    const float* W2   = (const float*)d_in[9];
    const float* b2   = (const float*)d_in[10];
    const float* W3   = (const float*)d_in[11];
    const float* b3   = (const float*)d_in[12];
    float* out = (float*)d_out;
    float* ws  = (float*)d_ws;

    // Workspace (float-slot offsets). Peak 10,076,720 floats = 40.3 MB
    // (42.9 MB proven safe in r5; r4's 53.1 MB overflowed).
    int*   cnt    = (int*)(ws);                                // 10,000
    int*   startA = (int*)(ws + 10000);                        // 10,000
    int*   cursor = (int*)(ws + 20000);                        // 10,000
    int*   sorted = (int*)(ws + 30000);                        // 160,000
    __hip_bfloat16* Mmat = (__hip_bfloat16*)(ws + 190000);     // 10000x1024 bf16
    __hip_bfloat16* embB = (__hip_bfloat16*)(ws + 5310000);    // 10000x256 bf16
    __hip_bfloat16* aghT = (__hip_bfloat16*)(ws + 6590000);    // 1024x256 bf16
    __hip_bfloat16* W1b  = (__hip_bfloat16*)(ws + 6721072);    // 256x640 bf16
    __hip_bfloat16* W2b  = (__hip_bfloat16*)(ws + 6802992);    // 256x256 bf16
    __hip_bfloat16* W3b  = (__hip_bfloat16*)(ws + 6835760);    // 320x256 bf16 (padded)
    __hip_bfloat16* comb = (__hip_bfloat16*)(ws + 6876720);    // 10000x640 bf16
    // end: 10,076,720 floats

    const int* idx_j = pidx + N_PAIRS;

    {   // conversions + transposes + cnt zeroing
        int blocks = (PREP_TOTAL + 255) / 256;
        prep_kernel<<<blocks, 256, 0, stream>>>(emb, W1, W2, agh, W3,
                                                embB, W1b, W2b, aghT, W3b, cnt);
    }
    {   // count-sort pairs by atom
        int blocks = (N_PAIRS + 255) / 256;
        hist_kernel<<<blocks, 256, 0, stream>>>(idx_j, cnt);
        scan_kernel<<<1, 1024, 0, stream>>>(cnt, startA, cursor);
        scatter_ids_kernel<<<blocks, 256, 0, stream>>>(idx_j, cursor, sorted);
    }
    {   // Mmat = embB @ aghT^T : (10000x256)@(256x1024) -> bf16
        dim3 grid((N_ATOMS + 63) / 64, 1024 / 64);
        gemm_mfma<N_ATOMS, 1024, 256><<<grid, 64, 0, stream>>>(
            (const short*)embB, (const short*)aghT, Mmat);
    }
    // fused gather + combined-builder (625 blocks)
    gather_build<<<(N_ATOMS + 15) / 16, 256, 0, stream>>>(
        sorted, startA, cnt, gs, gv, emb, q, W_gs, Mmat, comb);
    // fused 3-layer MLP + output remap (625 blocks)
    mlp_fused<<<(N_ATOMS + 15) / 16, 256, 0, stream>>>(
        (const short*)comb, (const short*)W1b, (const short*)W2b, (const short*)W3b,
        b1, b2, b3, out);
}

// Round 9
// 145.477 us; speedup vs baseline: 1.3594x; 1.0603x over previous
//
#include <hip/hip_runtime.h>
#include <hip/hip_bf16.h>
#include <math.h>

#define N_ATOMS 10000
#define N_PAIRS 160000
#define FDIM 256
#define GDIM 16
#define HDIM 64
#define HIDDIM 256
#define MLP_IN 640
#define MLP_OUT 258

typedef __attribute__((ext_vector_type(8))) short short8;
typedef __attribute__((ext_vector_type(4))) float f32x4;

__device__ __forceinline__ float gelu_exact(float x) {
    return 0.5f * x * (1.0f + erff(x * 0.70710678118654752f));
}
__device__ __forceinline__ short bf16bits(float x) {
    __hip_bfloat16 h = __float2bfloat16(x);
    return *reinterpret_cast<short*>(&h);
}

// ---------------------------------------------------------------------------
// Prep: emb->bf16 vectorized (8/thread), then scalar regions:
//   W1b(163840) W2b(65536) aghT(262144, transpose) W3b(81920, pad to 320) cnt(10000)
// ---------------------------------------------------------------------------
#define PREP_VEC 320000
#define PREP_TOTAL (PREP_VEC + 163840 + 65536 + 262144 + 81920 + 10000)
__global__ void prep_kernel(const float* __restrict__ emb,
                            const float* __restrict__ W1,
                            const float* __restrict__ W2,
                            const float* __restrict__ agh,
                            const float* __restrict__ W3,
                            __hip_bfloat16* __restrict__ embB,
                            __hip_bfloat16* __restrict__ W1b,
                            __hip_bfloat16* __restrict__ W2b,
                            __hip_bfloat16* __restrict__ aghT,
                            __hip_bfloat16* __restrict__ W3b,
                            int* __restrict__ cnt) {
    int tid = blockIdx.x * blockDim.x + threadIdx.x;
    if (tid >= PREP_TOTAL) return;
    int j = tid;
    if (j < PREP_VEC) {   // embB: 8 elems per thread, vectorized
        int base = j * 8;
        f32x4 v0 = *(const f32x4*)(emb + base);
        f32x4 v1 = *(const f32x4*)(emb + base + 4);
        short8 o;
        o[0] = bf16bits(v0[0]); o[1] = bf16bits(v0[1]);
        o[2] = bf16bits(v0[2]); o[3] = bf16bits(v0[3]);
        o[4] = bf16bits(v1[0]); o[5] = bf16bits(v1[1]);
        o[6] = bf16bits(v1[2]); o[7] = bf16bits(v1[3]);
        *(short8*)((short*)embB + base) = o;
        return;
    }
    j -= PREP_VEC;
    if (j < 163840) { W1b[j] = __float2bfloat16(W1[j]); return; }
    j -= 163840;
    if (j < 65536) { W2b[j] = __float2bfloat16(W2[j]); return; }
    j -= 65536;
    if (j < 262144) {
        int n = j >> 8, k = j & 255;
        aghT[j] = __float2bfloat16(agh[k * 1024 + n]);
        return;
    }
    j -= 262144;
    if (j < 81920) {   // W3b padded to 320x256
        int n = j >> 8;
        W3b[j] = (n < MLP_OUT) ? __float2bfloat16(W3[j]) : __float2bfloat16(0.f);
        return;
    }
    j -= 81920;
    cnt[j] = 0;
}

// ---------------------------------------------------------------------------
// Count-sort of pairs by destination atom: hist -> scan -> scatter_ids.
// ---------------------------------------------------------------------------
__global__ void hist_kernel(const int* __restrict__ idx_j, int* __restrict__ cnt) {
    int p = blockIdx.x * blockDim.x + threadIdx.x;
    if (p >= N_PAIRS) return;
    atomicAdd(&cnt[idx_j[p]], 1);
}

__global__ __launch_bounds__(1024) void scan_kernel(const int* __restrict__ cnt,
                                                    int* __restrict__ start,
                                                    int* __restrict__ cursor) {
    __shared__ int part[1024];
    int t = threadIdx.x;
    int base = t * 10;
    int pre[10];
    int sum = 0;
#pragma unroll
    for (int k = 0; k < 10; ++k) {
        int i = base + k;
        int v = (i < N_ATOMS) ? cnt[i] : 0;
        pre[k] = sum;
        sum += v;
    }
    part[t] = sum;
    __syncthreads();
    for (int off = 1; off < 1024; off <<= 1) {
        int v = (t >= off) ? part[t - off] : 0;
        __syncthreads();
        part[t] += v;
        __syncthreads();
    }
    int excl = (t == 0) ? 0 : part[t - 1];
#pragma unroll
    for (int k = 0; k < 10; ++k) {
        int i = base + k;
        if (i < N_ATOMS) {
            start[i]  = excl + pre[k];
            cursor[i] = excl + pre[k];
        }
    }
}

__global__ void scatter_ids_kernel(const int* __restrict__ idx_j,
                                   int* __restrict__ cursor,
                                   int* __restrict__ sorted) {
    int p = blockIdx.x * blockDim.x + threadIdx.x;
    if (p >= N_PAIRS) return;
    int i = idx_j[p];
    int pos = atomicAdd(&cursor[i], 1);
    sorted[pos] = p;
}

// ---------------------------------------------------------------------------
// bf16 MFMA GEMM (Mmat only): C[M,N] = A[M,K] @ B[N,K]^T, bf16 out.
// 64-thread blocks, one wave, 64x64 tile (4x4 frags). No LDS.
// ---------------------------------------------------------------------------
template<int M, int N, int K>
__global__ __launch_bounds__(64) void gemm_mfma(const short* __restrict__ A,
                                                const short* __restrict__ B,
                                                __hip_bfloat16* __restrict__ Cout) {
    int lane = threadIdx.x;
    int m0 = blockIdx.x * 64;
    int n0 = blockIdx.y * 64;
    int lr = lane & 15;
    int koff0 = (lane >> 4) * 8;

    f32x4 acc[4][4] = {};
    const short8 zero8 = {};

    const short* Arow[4];
    bool ok[4];
#pragma unroll
    for (int fm = 0; fm < 4; ++fm) {
        int row = m0 + fm * 16 + lr;
        ok[fm] = row < M;
        Arow[fm] = A + (long long)(ok[fm] ? row : 0) * K + koff0;
    }
    const short* Bb = B + (long long)(n0 + lr) * K + koff0;

#pragma unroll 2
    for (int ks = 0; ks < K; ks += 32) {
        short8 a[4], b[4];
#pragma unroll
        for (int fm = 0; fm < 4; ++fm)
            a[fm] = ok[fm] ? *(const short8*)(Arow[fm] + ks) : zero8;
#pragma unroll
        for (int fn = 0; fn < 4; ++fn)
            b[fn] = *(const short8*)(Bb + (long long)fn * 16 * K + ks);
#pragma unroll
        for (int fm = 0; fm < 4; ++fm)
#pragma unroll
            for (int fn = 0; fn < 4; ++fn)
                acc[fm][fn] = __builtin_amdgcn_mfma_f32_16x16x32_bf16(a[fm], b[fn],
                                                                      acc[fm][fn], 0, 0, 0);
    }

    int rbase = (lane >> 4) * 4;
#pragma unroll
    for (int fm = 0; fm < 4; ++fm) {
#pragma unroll
        for (int fn = 0; fn < 4; ++fn) {
            int col = n0 + fn * 16 + lr;
#pragma unroll
            for (int r = 0; r < 4; ++r) {
                int row = m0 + fm * 16 + rbase + r;
                if (row >= M) continue;
                Cout[(long long)row * N + col] = __float2bfloat16(acc[fm][fn][r]);
            }
        }
    }
}

// ---------------------------------------------------------------------------
// Fused gather + build_combined: 16 atoms per 256-thread block (grid 625).
// ---------------------------------------------------------------------------
__global__ __launch_bounds__(256) void gather_build(
        const int* __restrict__ sorted,
        const int* __restrict__ start,
        const int* __restrict__ cnt,
        const float* __restrict__ gs,
        const float* __restrict__ gv,
        const float* __restrict__ emb,
        const float* __restrict__ q,
        const float* __restrict__ W_gs,
        const __hip_bfloat16* __restrict__ Mmat,
        __hip_bfloat16* __restrict__ combined) {
    __shared__ float sW[FDIM * 17];
    __shared__ float sG[16][GDIM];
    __shared__ float sGV[16][48];
    int i0 = blockIdx.x * 16;
    int t = threadIdx.x;

    for (int j = t; j < FDIM * GDIM; j += 256)
        sW[(j >> 4) * 17 + (j & 15)] = W_gs[j];

    // Phase A: gather (16 lanes per atom)
    {
        int grp = t >> 4, l = t & 15;
        int atom = i0 + grp;
        int s = start[atom], c = cnt[atom];
        const float* base;
        long long stride;
        if (l < 4) { base = gs + l * 4;        stride = 16; }
        else       { base = gv + (l - 4) * 4;  stride = 48; }
        f32x4 acc = {0.f, 0.f, 0.f, 0.f};
        int j = 0;
        for (; j + 1 < c; j += 2) {
            int p0 = sorted[s + j];
            int p1 = sorted[s + j + 1];
            acc += *(const f32x4*)(base + p0 * stride);
            acc += *(const f32x4*)(base + p1 * stride);
        }
        if (j < c) {
            int p0 = sorted[s + j];
            acc += *(const f32x4*)(base + p0 * stride);
        }
        if (l < 4) *(f32x4*)&sG[grp][l * 4] = acc;
        else       *(f32x4*)&sGV[grp][(l - 4) * 4] = acc;
    }
    __syncthreads();

    float wreg[GDIM];
#pragma unroll
    for (int g = 0; g < GDIM; ++g) wreg[g] = sW[t * 17 + g];

    // radial_emb / radial_q (thread t owns feature f = t)
#pragma unroll 4
    for (int a = 0; a < 16; ++a) {
        int i = i0 + a;
        float S = 0.f;
#pragma unroll
        for (int g = 0; g < GDIM; ++g) S += sG[a][g] * wreg[g];
        float ev = emb[(long long)i * FDIM + t];
        float qq = q[i];
        __hip_bfloat16* crow = combined + (long long)i * MLP_IN;
        crow[t]       = __float2bfloat16(ev * S);
        crow[320 + t] = __float2bfloat16(qq * S);
    }

    // vector_emb: wave w handles atoms w, w+4, w+8, w+12; lanes cover h=0..63
#pragma unroll
    for (int r = 0; r < 4; ++r) {
        int a = (t >> 6) + r * 4;
        int h = t & 63;
        int i = i0 + a;
        float a0 = 0.f, a1 = 0.f, a2 = 0.f;
#pragma unroll
        for (int g = 0; g < GDIM; ++g) {
            float mg = __bfloat162float(Mmat[(long long)i * 1024 + g * 64 + h]);
            a0 += mg * sGV[a][g];
            a1 += mg * sGV[a][16 + g];
            a2 += mg * sGV[a][32 + g];
        }
        __hip_bfloat16* crow = combined + (long long)i * MLP_IN;
        crow[256 + h] = __float2bfloat16(sqrtf(a0 * a0 + a1 * a1 + a2 * a2));
        crow[576 + h] = __float2bfloat16(0.f);
    }
}

// ---------------------------------------------------------------------------
// Fused MLP v2: 64 atoms per 512-thread block (8 waves), grid 157.
// Each B(weight)-load now feeds 4 MFMAs (was 1): phases 1-2 give wave w
// cols [32w, 32w+32) x all 64 rows -> per K-step 4 A-loads + 2 B-loads
// -> 8 MFMA. Phase 3 (320 padded cols = 20 frags): wave w takes frags
// {w, w+8, w+16(w<4)}. h1/h2 in LDS (64x264 bf16 each). Last-block rows
// clamped on load, guarded on store.
// ---------------------------------------------------------------------------
__global__ __launch_bounds__(512) void mlp_fused(
        const short* __restrict__ comb,
        const short* __restrict__ W1b,
        const short* __restrict__ W2b,
        const short* __restrict__ W3b,
        const float* __restrict__ b1,
        const float* __restrict__ b2,
        const float* __restrict__ b3,
        float* __restrict__ outp) {
    __shared__ short h1s[64][264];
    __shared__ short h2s[64][264];
    int lane = threadIdx.x & 63;
    int wave = threadIdx.x >> 6;
    int m0 = blockIdx.x * 64;
    int lr = lane & 15;
    int ko = (lane >> 4) * 8;
    int rbase = (lane >> 4) * 4;

    // Clamped A-row pointers (rows >= N_ATOMS read row N_ATOMS-1; discarded at store)
    const short* Arow[4];
#pragma unroll
    for (int fm = 0; fm < 4; ++fm) {
        int row = m0 + fm * 16 + lr;
        if (row >= N_ATOMS) row = N_ATOMS - 1;
        Arow[fm] = comb + (long long)row * MLP_IN + ko;
    }

    // Phase 1: h1 = gelu(comb @ W1^T + b1); wave cols [32w, 32w+32)
    {
        f32x4 acc[4][2] = {};
        const short* Bb = W1b + (long long)(wave * 32 + lr) * MLP_IN + ko;
#pragma unroll 4
        for (int ks = 0; ks < MLP_IN; ks += 32) {
            short8 a[4], b[2];
#pragma unroll
            for (int fm = 0; fm < 4; ++fm) a[fm] = *(const short8*)(Arow[fm] + ks);
#pragma unroll
            for (int fn = 0; fn < 2; ++fn)
                b[fn] = *(const short8*)(Bb + (long long)fn * 16 * MLP_IN + ks);
#pragma unroll
            for (int fm = 0; fm < 4; ++fm)
#pragma unroll
                for (int fn = 0; fn < 2; ++fn)
                    acc[fm][fn] = __builtin_amdgcn_mfma_f32_16x16x32_bf16(a[fm], b[fn],
                                                                          acc[fm][fn], 0, 0, 0);
        }
#pragma unroll
        for (int fn = 0; fn < 2; ++fn) {
            int col = wave * 32 + fn * 16 + lr;
            float bias = b1[col];
#pragma unroll
            for (int fm = 0; fm < 4; ++fm)
#pragma unroll
                for (int r = 0; r < 4; ++r)
                    h1s[fm * 16 + rbase + r][col] = bf16bits(gelu_exact(acc[fm][fn][r] + bias));
        }
    }
    __syncthreads();

    // Phase 2: h2 = gelu(h1 @ W2^T + b2); A from LDS
    {
        f32x4 acc[4][2] = {};
        const short* Bb = W2b + (long long)(wave * 32 + lr) * HIDDIM + ko;
#pragma unroll
        for (int ks = 0; ks < HIDDIM; ks += 32) {
            short8 a[4], b[2];
#pragma unroll
            for (int fm = 0; fm < 4; ++fm)
                a[fm] = *(const short8*)(&h1s[fm * 16 + lr][ko + ks]);
#pragma unroll
            for (int fn = 0; fn < 2; ++fn)
                b[fn] = *(const short8*)(Bb + (long long)fn * 16 * HIDDIM + ks);
#pragma unroll
            for (int fm = 0; fm < 4; ++fm)
#pragma unroll
                for (int fn = 0; fn < 2; ++fn)
                    acc[fm][fn] = __builtin_amdgcn_mfma_f32_16x16x32_bf16(a[fm], b[fn],
                                                                          acc[fm][fn], 0, 0, 0);
        }
#pragma unroll
        for (int fn = 0; fn < 2; ++fn) {
            int col = wave * 32 + fn * 16 + lr;
            float bias = b2[col];
#pragma unroll
            for (int fm = 0; fm < 4; ++fm)
#pragma unroll
                for (int r = 0; r < 4; ++r)
                    h2s[fm * 16 + rbase + r][col] = bf16bits(gelu_exact(acc[fm][fn][r] + bias));
        }
    }
    __syncthreads();

    // Phase 3: out = h2 @ W3^T + b3 (320 padded cols = 20 frags);
    // wave w -> frags w, w+8, and (w<4) w+16. Remap (delta_a | delta_q | f).
    {
        int f0 = wave, f1 = wave + 8, f2 = wave + 16;
        bool has2 = (wave < 4);
        f32x4 acc0[4] = {}, acc1[4] = {}, acc2[4] = {};
        const short* B0 = W3b + (long long)(f0 * 16 + lr) * HIDDIM + ko;
        const short* B1 = W3b + (long long)(f1 * 16 + lr) * HIDDIM + ko;
        const short* B2 = W3b + (long long)((has2 ? f2 : f0) * 16 + lr) * HIDDIM + ko;
#pragma unroll
        for (int ks = 0; ks < HIDDIM; ks += 32) {
            short8 a[4];
#pragma unroll
            for (int fm = 0; fm < 4; ++fm)
                a[fm] = *(const short8*)(&h2s[fm * 16 + lr][ko + ks]);
            short8 b0 = *(const short8*)(B0 + ks);
            short8 b1v = *(const short8*)(B1 + ks);
#pragma unroll
            for (int fm = 0; fm < 4; ++fm) {
                acc0[fm] = __builtin_amdgcn_mfma_f32_16x16x32_bf16(a[fm], b0, acc0[fm], 0, 0, 0);
                acc1[fm] = __builtin_amdgcn_mfma_f32_16x16x32_bf16(a[fm], b1v, acc1[fm], 0, 0, 0);
            }
            if (has2) {
                short8 b2v = *(const short8*)(B2 + ks);
#pragma unroll
                for (int fm = 0; fm < 4; ++fm)
                    acc2[fm] = __builtin_amdgcn_mfma_f32_16x16x32_bf16(a[fm], b2v, acc2[fm], 0, 0, 0);
            }
        }
#pragma unroll
        for (int slot = 0; slot < 3; ++slot) {
            if (slot == 2 && !has2) continue;
            int f = (slot == 0) ? f0 : (slot == 1) ? f1 : f2;
            int col = f * 16 + lr;
            if (col >= MLP_OUT) continue;
            float bias = b3[col];
#pragma unroll
            for (int fm = 0; fm < 4; ++fm) {
#pragma unroll
                for (int r = 0; r < 4; ++r) {
                    int row = m0 + fm * 16 + rbase + r;
                    if (row >= N_ATOMS) continue;
                    f32x4 av = (slot == 0) ? acc0[fm] : (slot == 1) ? acc1[fm] : acc2[fm];
                    float v = av[r] + bias;
                    if (col == 0)      outp[2560000 + row] = v;
                    else if (col == 1) outp[2570000 + row] = v;
                    else               outp[(long long)row * 256 + (col - 2)] = v;
                }
            }
        }
    }
}

extern "C" void kernel_launch(void* const* d_in, const int* in_sizes, int n_in,
                              void* d_out, int out_size, void* d_ws, size_t ws_size,
                              hipStream_t stream) {
    const float* emb  = (const float*)d_in[0];
    const float* q    = (const float*)d_in[1];
    const int*   pidx = (const int*)d_in[2];
    const float* gs   = (const float*)d_in[3];
    const float* gv   = (const float*)d_in[4];
    const float* agh  = (const float*)d_in[5];
    const float* W_gs = (const float*)d_in[6];
    const float* W1   = (const float*)d_in[7];
    const float* b1   = (const float*)d_in[8];
    const float* W2   = (const float*)d_in[9];
    const float* b2   = (const float*)d_in[10];
    const float* W3   = (const float*)d_in[11];
    const float* b3   = (const float*)d_in[12];
    float* out = (float*)d_out;
    float* ws  = (float*)d_ws;

    // Workspace (float-slot offsets). Peak 10,076,720 floats = 40.3 MB
    // (42.9 MB proven safe in r5; r4's 53.1 MB overflowed).
    int*   cnt    = (int*)(ws);                                // 10,000
    int*   startA = (int*)(ws + 10000);                        // 10,000
    int*   cursor = (int*)(ws + 20000);                        // 10,000
    int*   sorted = (int*)(ws + 30000);                        // 160,000
    __hip_bfloat16* Mmat = (__hip_bfloat16*)(ws + 190000);     // 10000x1024 bf16
    __hip_bfloat16* embB = (__hip_bfloat16*)(ws + 5310000);    // 10000x256 bf16
    __hip_bfloat16* aghT = (__hip_bfloat16*)(ws + 6590000);    // 1024x256 bf16
    __hip_bfloat16* W1b  = (__hip_bfloat16*)(ws + 6721072);    // 256x640 bf16
    __hip_bfloat16* W2b  = (__hip_bfloat16*)(ws + 6802992);    // 256x256 bf16
    __hip_bfloat16* W3b  = (__hip_bfloat16*)(ws + 6835760);    // 320x256 bf16 (padded)
    __hip_bfloat16* comb = (__hip_bfloat16*)(ws + 6876720);    // 10000x640 bf16
    // end: 10,076,720 floats

    const int* idx_j = pidx + N_PAIRS;

    {   // conversions + transposes + cnt zeroing
        int blocks = (PREP_TOTAL + 255) / 256;
        prep_kernel<<<blocks, 256, 0, stream>>>(emb, W1, W2, agh, W3,
                                                embB, W1b, W2b, aghT, W3b, cnt);
    }
    {   // count-sort pairs by atom
        int blocks = (N_PAIRS + 255) / 256;
        hist_kernel<<<blocks, 256, 0, stream>>>(idx_j, cnt);
        scan_kernel<<<1, 1024, 0, stream>>>(cnt, startA, cursor);
        scatter_ids_kernel<<<blocks, 256, 0, stream>>>(idx_j, cursor, sorted);
    }
    {   // Mmat = embB @ aghT^T : (10000x256)@(256x1024) -> bf16
        dim3 grid((N_ATOMS + 63) / 64, 1024 / 64);
        gemm_mfma<N_ATOMS, 1024, 256><<<grid, 64, 0, stream>>>(
            (const short*)embB, (const short*)aghT, Mmat);
    }
    // fused gather + combined-builder (625 blocks)
    gather_build<<<(N_ATOMS + 15) / 16, 256, 0, stream>>>(
        sorted, startA, cnt, gs, gv, emb, q, W_gs, Mmat, comb);
    // fused 3-layer MLP + output remap (157 blocks x 512 thr)
    mlp_fused<<<(N_ATOMS + 63) / 64, 512, 0, stream>>>(
        (const short*)comb, (const short*)W1b, (const short*)W2b, (const short*)W3b,
        b1, b2, b3, out);
}